// Round 14
// baseline (1095.726 us; speedup 1.0000x reference)
//
#include <hip/hip_runtime.h>
#include <hip/hip_bf16.h>
#include <math.h>

#define L_TOK 138240
#define NW 960

typedef __attribute__((ext_vector_type(8))) short s16x8;
typedef __attribute__((ext_vector_type(8))) unsigned short u16x8;
typedef __attribute__((ext_vector_type(4))) unsigned short u16x4;
typedef __attribute__((ext_vector_type(4))) float f32x4;

__device__ __forceinline__ float bf2f(unsigned short u){
  union{unsigned int u;float f;} v; v.u=((unsigned int)u)<<16; return v.f;
}
__device__ __forceinline__ unsigned short f2bf(float f){
  __hip_bfloat16 b = __float2bfloat16(f);
  union { __hip_bfloat16 b; unsigned short u; } v; v.b = b; return v.u;
}
__device__ __forceinline__ void gll16(const void* g, void* l) {
  __builtin_amdgcn_global_load_lds((const __attribute__((address_space(1))) void*)g,
                                   (__attribute__((address_space(3))) void*)l, 16, 0, 0);
}
// exact-gelu via A&S 7.1.26 erf (max abs err 1.5e-7 << bf16 ulp)
__device__ __forceinline__ float gelu_f(float v){
  const float s = v * 0.70710678118654752f;
  const float a = fabsf(s);
  const float t = 1.0f / (1.0f + 0.3275911f * a);
  float p = 1.061405429f;
  p = p*t - 1.453152027f;
  p = p*t + 1.421413741f;
  p = p*t - 0.284496736f;
  p = p*t + 0.254829592f;
  p = p*t;
  float y = 1.0f - p * __expf(-a*a);
  y = copysignf(y, s);
  return 0.5f * v * (1.0f + y);
}

// ============ QKV GEMM: A = xb bf16 (gll16, swizzled), 64-row stripes ============
template<int NTILES>
__global__ __launch_bounds__(256) void gemm_qkv(
    const unsigned short* __restrict__ xb,   // L x 192 bf16
    const unsigned short* __restrict__ Bt,   // N x 192 bf16
    const float* __restrict__ bias,
    unsigned short* __restrict__ out)        // L x N
{
  __shared__ unsigned short As[64*192];      // linear, swizzled via global src
  const int tid = threadIdx.x;
  const int wid = tid >> 6, lane = tid & 63;
  const int lr = lane & 15, kg = lane >> 4;
  const int bm = blockIdx.x;
  const int wn = wid * 16;
  const int N = NTILES * 64;

  #pragma unroll
  for (int i = 0; i < 6; i++) {
    const int c = tid + i*256;
    const int r = c / 24, s = c % 24;
    const int sg = (s & 24) | ((s ^ r) & 7);   // pre-swizzled source slot
    gll16(&xb[(size_t)(bm*64 + r)*192 + sg*8], &As[c*8]);
  }
  __syncthreads();

  s16x8 a[4][6];
  #pragma unroll
  for (int mi = 0; mi < 4; mi++)
    #pragma unroll
    for (int ks = 0; ks < 6; ks++) {
      const int m = mi*16 + lr, g = ks*4 + kg;
      const int sg = (g & 24) | ((g ^ m) & 7);
      a[mi][ks] = *(const s16x8*)&As[m*192 + sg*8];
    }

  for (int bn = 0; bn < NTILES; bn++) {
    s16x8 b[6];
    #pragma unroll
    for (int ks = 0; ks < 6; ks++)
      b[ks] = *(const s16x8*)&Bt[(size_t)(bn*64 + wn + lr)*192 + ks*32 + kg*8];
    f32x4 acc[4] = {};
    #pragma unroll
    for (int ks = 0; ks < 6; ks++)
      #pragma unroll
      for (int mi = 0; mi < 4; mi++)
        acc[mi] = __builtin_amdgcn_mfma_f32_16x16x32_bf16(a[mi][ks], b[ks], acc[mi], 0, 0, 0);
    const int col = bn*64 + wn + lr;
    const float bv = bias[col];
    #pragma unroll
    for (int mi = 0; mi < 4; mi++)
      #pragma unroll
      for (int q = 0; q < 4; q++) {
        const int row = bm*64 + mi*16 + kg*4 + q;
        out[(size_t)row*N + col] = f2bf(acc[mi][q] + bv);
      }
  }
}

// ============ proj GEMM + LN residual: xb += LN(A @ Bt^T + bias) (bf16 RMW) ============
__global__ __launch_bounds__(256) void gemm_ln(
    const unsigned short* __restrict__ A,    // rows at stride lda (AO in R0)
    const unsigned short* __restrict__ Bt,   // 192 x 192 bf16
    const float* __restrict__ bias, const float* __restrict__ g,
    const float* __restrict__ bta,
    unsigned short* __restrict__ xbo,
    int lda)
{
  __shared__ unsigned short As[2][128*32];
  __shared__ unsigned short Bs[2][192*32];
  __shared__ float rowstat[128][2][2];
  const int tid = threadIdx.x;
  const int wid = tid >> 6, lane = tid & 63;
  const int lr = lane & 15, kg = lane >> 4;
  const int bm = blockIdx.x;
  const int wm = (wid >> 1) * 64, wn = (wid & 1) * 96;
  const int rsub = lane >> 2, kc = lane & 3;
  const int K = 192;

  f32x4 acc[4][6] = {};
  const int nst = K / 32;

  #pragma unroll
  for (int i = 0; i < 2; i++)
    gll16(&A[(size_t)(bm*128 + wid*32 + i*16 + rsub)*lda + kc*8], &As[0][(wid*32 + i*16)*32]);
  #pragma unroll
  for (int j = 0; j < 3; j++)
    gll16(&Bt[(size_t)(wid*48 + j*16 + rsub)*K + kc*8], &Bs[0][(wid*48 + j*16)*32]);
  __syncthreads();

  for (int t = 0; t < nst; t++) {
    const int cur = t & 1, nxt = cur ^ 1;
    if (t + 1 < nst) {
      const int k1 = (t+1)*32;
      #pragma unroll
      for (int i = 0; i < 2; i++)
        gll16(&A[(size_t)(bm*128 + wid*32 + i*16 + rsub)*lda + k1 + kc*8], &As[nxt][(wid*32 + i*16)*32]);
      #pragma unroll
      for (int j = 0; j < 3; j++)
        gll16(&Bt[(size_t)(wid*48 + j*16 + rsub)*K + k1 + kc*8], &Bs[nxt][(wid*48 + j*16)*32]);
    }
    s16x8 a[4], b[6];
    #pragma unroll
    for (int mi = 0; mi < 4; mi++) a[mi] = *(const s16x8*)&As[cur][(wm + mi*16 + lr)*32 + kg*8];
    #pragma unroll
    for (int ni = 0; ni < 6; ni++) b[ni] = *(const s16x8*)&Bs[cur][(wn + ni*16 + lr)*32 + kg*8];
    #pragma unroll
    for (int mi = 0; mi < 4; mi++)
      #pragma unroll
      for (int ni = 0; ni < 6; ni++)
        acc[mi][ni] = __builtin_amdgcn_mfma_f32_16x16x32_bf16(a[mi], b[ni], acc[mi][ni], 0, 0, 0);
    __syncthreads();
  }

  float bv[6], gv[6], btv[6];
  #pragma unroll
  for (int ni = 0; ni < 6; ni++) {
    const int col = wn + ni*16 + lr;
    bv[ni] = bias[col]; gv[ni] = g[col]; btv[ni] = bta[col];
  }
  #pragma unroll
  for (int mi = 0; mi < 4; mi++) {
    float s[4] = {0,0,0,0}, ss[4] = {0,0,0,0};
    #pragma unroll
    for (int ni = 0; ni < 6; ni++)
      #pragma unroll
      for (int q = 0; q < 4; q++) {
        const float v = acc[mi][ni][q] + bv[ni];
        s[q] += v; ss[q] += v*v;
      }
    #pragma unroll
    for (int q = 0; q < 4; q++) {
      #pragma unroll
      for (int m = 1; m < 16; m <<= 1) {
        s[q]  += __shfl_xor(s[q],  m, 64);
        ss[q] += __shfl_xor(ss[q], m, 64);
      }
    }
    if (lr == 0) {
      #pragma unroll
      for (int q = 0; q < 4; q++) {
        const int r = wm + mi*16 + kg*4 + q;
        rowstat[r][wid & 1][0] = s[q];
        rowstat[r][wid & 1][1] = ss[q];
      }
    }
  }
  __syncthreads();
  #pragma unroll
  for (int mi = 0; mi < 4; mi++) {
    #pragma unroll
    for (int q = 0; q < 4; q++) {
      const int rl = wm + mi*16 + kg*4 + q;
      const float s  = rowstat[rl][0][0] + rowstat[rl][1][0];
      const float ss = rowstat[rl][0][1] + rowstat[rl][1][1];
      const float mu = s * (1.0f/192.0f);
      const float rs = rsqrtf(ss * (1.0f/192.0f) - mu*mu + 1e-5f);
      const size_t grow = (size_t)(bm*128 + rl) * 192;
      #pragma unroll
      for (int ni = 0; ni < 6; ni++) {
        const float v = acc[mi][ni][q] + bv[ni];
        const float o = (v - mu) * rs * gv[ni] + btv[ni];
        const size_t idx = grow + wn + ni*16 + lr;
        xbo[idx] = f2bf(bf2f(xbo[idx]) + o);
      }
    }
  }
}

// ============ Fused MLP (BM=32, high occupancy): xb += LN(gelu(xb@W1+b1)@W2+b2) ============
template<int WF32>
__global__ __launch_bounds__(256) void fused_mlp(
    const unsigned short* __restrict__ xb,   // L x 192 bf16 (also RMW target)
    const unsigned short* __restrict__ W1t,  // 768 x 192 bf16
    const unsigned short* __restrict__ W2t,  // 192 x 768 bf16
    const float* __restrict__ b1, const float* __restrict__ b2,
    const float* __restrict__ g, const float* __restrict__ bt,
    unsigned short* __restrict__ xbo, float* __restrict__ xf)
{
  __shared__ unsigned short As[32*192];      // swizzled (via global src), 12 KB
  __shared__ unsigned short Hs[32*64];       // [m][hcol] 128B rows, XOR-swizzled, 4 KB
  __shared__ float rowstat[32][4][2];
  const int tid = threadIdx.x, wid = tid >> 6, lane = tid & 63;
  const int lr = lane & 15, kg = lane >> 4;
  const int row0 = blockIdx.x * 32;

  #pragma unroll
  for (int i = 0; i < 3; i++) {
    const int c = tid + i*256;
    const int r = c / 24, s = c % 24;
    const int sg = (s & 24) | ((s ^ r) & 7);
    gll16(&xb[(size_t)(row0 + r)*192 + sg*8], &As[c*8]);
  }
  __syncthreads();

  char* const hs = (char*)&Hs[0];

  f32x4 yacc[2][3] = {};
  // prefetch W1 fragments for t=0
  s16x8 w1f[6];
  #pragma unroll
  for (int ks = 0; ks < 6; ks++)
    w1f[ks] = *(const s16x8*)&W1t[(size_t)(wid*16 + lr)*192 + ks*32 + kg*8];

  for (int t = 0; t < 12; t++) {
    // GEMM1 (swapped): h^T = mfma(W1 rows=h-cols, x rows=m)
    f32x4 hacc[2];
    #pragma unroll
    for (int mb = 0; mb < 2; mb++) {
      const int m = mb*16 + lr;
      hacc[mb] = f32x4{0.f, 0.f, 0.f, 0.f};
      #pragma unroll
      for (int ks = 0; ks < 6; ks++) {
        const int gsl = ks*4 + kg;
        const int sg = (gsl & 24) | ((gsl ^ m) & 7);
        const s16x8 xf8 = *(const s16x8*)&As[m*192 + sg*8];
        hacc[mb] = __builtin_amdgcn_mfma_f32_16x16x32_bf16(w1f[ks], xf8, hacc[mb], 0, 0, 0);
      }
    }
    // prefetch GEMM2 weight fragments for this t (off the barrier path)
    s16x8 b2f[6];
    #pragma unroll
    for (int kk = 0; kk < 2; kk++)
      #pragma unroll
      for (int nj = 0; nj < 3; nj++)
        b2f[kk*3 + nj] = *(const s16x8*)&W2t[(size_t)(wid*48 + nj*16 + lr)*768 + t*64 + kk*32 + kg*8];

    const float4 b1q = *(const float4*)&b1[t*64 + wid*16 + kg*4];
    u16x4 hv[2];
    #pragma unroll
    for (int mb = 0; mb < 2; mb++) {
      hv[mb][0] = f2bf(gelu_f(hacc[mb][0] + b1q.x));
      hv[mb][1] = f2bf(gelu_f(hacc[mb][1] + b1q.y));
      hv[mb][2] = f2bf(gelu_f(hacc[mb][2] + b1q.z));
      hv[mb][3] = f2bf(gelu_f(hacc[mb][3] + b1q.w));
    }
    __syncthreads();                       // prior GEMM2 reads done
    {
      const int cb = wid*32 + kg*8;
      #pragma unroll
      for (int mb = 0; mb < 2; mb++) {
        const int m = mb*16 + lr;
        *(u16x4*)(hs + m*128 + (cb ^ ((m & 7) << 4))) = hv[mb];
      }
    }
    __syncthreads();                       // Hs ready
    // prefetch next-t W1 fragments (off the GEMM2 path)
    if (t < 11) {
      #pragma unroll
      for (int ks = 0; ks < 6; ks++)
        w1f[ks] = *(const s16x8*)&W1t[(size_t)((t+1)*64 + wid*16 + lr)*192 + ks*32 + kg*8];
    }
    // GEMM2: y += h_tile @ W2[:, t*64..]
    #pragma unroll
    for (int kk = 0; kk < 2; kk++) {
      #pragma unroll
      for (int mi = 0; mi < 2; mi++) {
        const int m = mi*16 + lr;
        const int cb2 = kk*64 + kg*16;
        const s16x8 a2 = *(const s16x8*)(hs + m*128 + (cb2 ^ ((m & 7) << 4)));
        #pragma unroll
        for (int nj = 0; nj < 3; nj++)
          yacc[mi][nj] = __builtin_amdgcn_mfma_f32_16x16x32_bf16(a2, b2f[kk*3 + nj], yacc[mi][nj], 0, 0, 0);
      }
    }
  }

  float bv[3], gv[3], btv[3];
  #pragma unroll
  for (int nj = 0; nj < 3; nj++) {
    const int col = wid*48 + nj*16 + lr;
    bv[nj] = b2[col]; gv[nj] = g[col]; btv[nj] = bt[col];
  }
  #pragma unroll
  for (int mi = 0; mi < 2; mi++) {
    float s[4] = {0,0,0,0}, ss[4] = {0,0,0,0};
    #pragma unroll
    for (int nj = 0; nj < 3; nj++)
      #pragma unroll
      for (int q = 0; q < 4; q++) {
        const float v = yacc[mi][nj][q] + bv[nj];
        s[q] += v; ss[q] += v*v;
      }
    #pragma unroll
    for (int q = 0; q < 4; q++) {
      #pragma unroll
      for (int m = 1; m < 16; m <<= 1) {
        s[q]  += __shfl_xor(s[q],  m, 64);
        ss[q] += __shfl_xor(ss[q], m, 64);
      }
    }
    if (lr == 0) {
      #pragma unroll
      for (int q = 0; q < 4; q++) {
        rowstat[mi*16 + kg*4 + q][wid][0] = s[q];
        rowstat[mi*16 + kg*4 + q][wid][1] = ss[q];
      }
    }
  }
  __syncthreads();
  #pragma unroll
  for (int mi = 0; mi < 2; mi++) {
    #pragma unroll
    for (int q = 0; q < 4; q++) {
      const int rl = mi*16 + kg*4 + q;
      const float s  = rowstat[rl][0][0] + rowstat[rl][1][0] + rowstat[rl][2][0] + rowstat[rl][3][0];
      const float ss = rowstat[rl][0][1] + rowstat[rl][1][1] + rowstat[rl][2][1] + rowstat[rl][3][1];
      const float mu = s * (1.0f/192.0f);
      const float rs = rsqrtf(ss * (1.0f/192.0f) - mu*mu + 1e-5f);
      const size_t grow = (size_t)(row0 + rl) * 192;
      #pragma unroll
      for (int nj = 0; nj < 3; nj++) {
        const float v = yacc[mi][nj][q] + bv[nj];
        const float o = (v - mu) * rs * gv[nj] + btv[nj];
        const size_t idx = grow + wid*48 + nj*16 + lr;
        const float xn = bf2f(xbo[idx]) + o;
        xbo[idx] = f2bf(xn);
        if (WF32) xf[idx] = xn;
      }
    }
  }
}

// ============ Window attention v7: in-place output over Q-slice of qkv ============
__global__ __launch_bounds__(384) void attn_win7(
    unsigned short* qkv,                       // L x 576 bf16 (Q pre-scaled; Q-slice overwritten)
    const unsigned short* __restrict__ biasbt, // [class][head][s][ti][lr][c4] bf16
    int roll)
{
  __shared__ unsigned short Pw[6][16][168];
  __shared__ int lmap[144];

  const int w = blockIdx.x;
  const int tid = threadIdx.x, wid = tid / 64, lane = tid & 63;
  const int lr = lane & 15, kg = lane >> 4;
  const int ww = w % 15, hw = (w / 15) % 16, zw = w / 240;

  if (tid < 144) {
    const int z1 = tid / 72, h1 = (tid % 72) / 12, w1 = tid % 12;
    int z = zw*2 + z1, h = hw*6 + h1, xx = ww*12 + w1;
    if (roll) { z = (z + 1) & 7; h = (h + 3) % 96; xx = (xx + 6) % 180; }
    lmap[tid] = (z*96 + h)*180 + xx;
  }
  __syncthreads();

  const unsigned short* bb;
  if (roll) {
    const int c = ((zw == 3) ? 2 : 0) | ((hw == 15) ? 1 : 0);
    bb = biasbt + (size_t)c*124416 + (size_t)wid*20736;
  } else {
    bb = biasbt + (size_t)wid*20736;
  }

  s16x8 kfr[9];
  #pragma unroll
  for (int ti = 0; ti < 9; ti++)
    kfr[ti] = *(const s16x8*)&qkv[(size_t)lmap[ti*16 + lr]*576 + 192 + wid*32 + kg*8];

  s16x8 vbr[2][5];
  #pragma unroll
  for (int ci = 0; ci < 2; ci++)
    #pragma unroll
    for (int ks = 0; ks < 5; ks++) {
      u16x8 t;
      #pragma unroll
      for (int j = 0; j < 8; j++) {
        const int tok = ks*32 + kg*8 + j;
        t[j] = (tok < 144) ? qkv[(size_t)lmap[tok]*576 + 384 + wid*32 + ci*16 + lr] : (unsigned short)0;
      }
      vbr[ci][ks] = (s16x8)t;
    }

  #pragma unroll
  for (int j = 0; j < 4; j++) Pw[wid][lr][144 + kg*4 + j] = 0;

  for (int s = 0; s < 9; s++) {
    const s16x8 bq = *(const s16x8*)&qkv[(size_t)lmap[s*16 + lr]*576 + wid*32 + kg*8];

    float pb[9][4];
    float mx = -3.0e38f;
    #pragma unroll
    for (int ti = 0; ti < 9; ti++) {
      f32x4 acc = {0.f, 0.f, 0.f, 0.f};
      acc = __builtin_amdgcn_mfma_f32_16x16x32_bf16(kfr[ti], bq, acc, 0, 0, 0);
      const u16x4 b4 = *(const u16x4*)&bb[(size_t)(s*9 + ti)*256 + lr*16 + kg*4];
      #pragma unroll
      for (int q = 0; q < 4; q++) {
        const float sv = acc[q] + bf2f(b4[q]);
        pb[ti][q] = sv;
        mx = fmaxf(mx, sv);
      }
    }
    mx = fmaxf(mx, __shfl_xor(mx, 16, 64));
    mx = fmaxf(mx, __shfl_xor(mx, 32, 64));

    float sum = 0.f;
    #pragma unroll
    for (int ti = 0; ti < 9; ti++)
      #pragma unroll
      for (int q = 0; q < 4; q++) {
        const float p = __expf(pb[ti][q] - mx);
        pb[ti][q] = p;
        sum += p;
      }
    sum += __shfl_xor(sum, 16, 64);
    sum += __shfl_xor(sum, 32, 64);
    const float inv = 1.0f / sum;

    #pragma unroll
    for (int ti = 0; ti < 9; ti++)
      #pragma unroll
      for (int q = 0; q < 4; q++)
        Pw[wid][lr][ti*16 + kg*4 + q] = f2bf(pb[ti][q] * inv);

    #pragma unroll
    for (int ci = 0; ci < 2; ci++) {
      f32x4 accO = {0.f, 0.f, 0.f, 0.f};
      #pragma unroll
      for (int ks = 0; ks < 5; ks++) {
        const s16x8 pa = *(const s16x8*)&Pw[wid][lr][ks*32 + kg*8];
        accO = __builtin_amdgcn_mfma_f32_16x16x32_bf16(pa, vbr[ci][ks], accO, 0, 0, 0);
      }
      #pragma unroll
      for (int q = 0; q < 4; q++) {
        const int row = s*16 + kg*4 + q;
        qkv[(size_t)lmap[row]*576 + wid*32 + ci*16 + lr] = f2bf(accO[q]);
      }
    }
  }
}

// ============ helpers ============
__global__ void init_xb(const float* __restrict__ xin, unsigned short* __restrict__ xb, int n) {
  const int i = blockIdx.x*256 + threadIdx.x;
  if (i < n) xb[i] = f2bf(xin[i]);
}
__global__ void copy_diag(const float* __restrict__ a, float* __restrict__ o, int n) {
  const int i = blockIdx.x*256 + threadIdx.x;
  if (i < n) o[i] = a[i] + 50.0f;
}
__global__ void transpose_w(const float* __restrict__ src, unsigned short* __restrict__ dst,
                            int K, int N, int nscale, float factor) {
  const int i = blockIdx.x*256 + threadIdx.x;
  const int tot = K*N;
  if (i >= 2*tot) return;
  const int l = i / tot, e = i % tot;
  const int k = e / N, n = e % N;
  float v = src[i];
  if (n < nscale) v *= factor;
  dst[(size_t)l*tot + (size_t)n*K + k] = f2bf(v);
}
__global__ void scale_qb(const float* __restrict__ src, float* __restrict__ dst) {
  const int i = blockIdx.x*256 + threadIdx.x;
  if (i >= 2*576) return;
  const float f = (i % 576) < 192 ? 0.17677669529663687f : 1.0f;
  dst[i] = src[i] * f;
}
// 5 tables lane-coalesced: [tau][head][s(9)][ti(9)][lr(16)][c4(16)]
__global__ void build_biasb6(const float* __restrict__ tab, unsigned short* __restrict__ bm) {
  const int i = blockIdx.x*256 + threadIdx.x;
  const int TAB = 6*144*144;
  if (i >= 5*TAB) return;
  const int tau = i / TAB, r = i % TAB;
  const int hd = r / 20736, rr = r % 20736;
  const int s = rr / 2304, rrr = rr % 2304;
  const int ti = rrr / 256, e = rrr % 256;
  const int lr_ = e / 16, c4 = e % 16;
  const int q = s*16 + lr_, tok = ti*16 + c4;
  const int z1 = q/72,  h1 = (q%72)/12,  w1 = q%12;
  const int z2 = tok/72, h2 = (tok%72)/12, w2 = tok%12;
  const int idx = (z1 + 2*z2)*828 + (h1 + 6*h2)*23 + (w1 - w2 + 11);
  const int l = (tau == 0) ? 0 : 1;
  float v = tab[(size_t)l*3312*6 + (size_t)idx*6 + hd];
  if (tau >= 1) {
    const int c = tau - 1, zs = c >> 1, hs = c & 1;
    const int rq = (zs ? (1 + z1) : 0)*3 + (hs ? (1 + (h1 >= 3)) : 0);
    const int rt = (zs ? (1 + z2) : 0)*3 + (hs ? (1 + (h2 >= 3)) : 0);
    if (rq != rt) v -= 1.0e9f;
  }
  bm[i] = f2bf(v);
}

extern "C" void kernel_launch(void* const* d_in, const int* in_sizes, int n_in,
                              void* d_out, int out_size, void* d_ws, size_t ws_size,
                              hipStream_t stream) {
  const float* x_in    = (const float*)d_in[0];
  const float* qkv_w   = (const float*)d_in[1];
  const float* qkv_b   = (const float*)d_in[2];
  const float* proj_w  = (const float*)d_in[3];
  const float* proj_b  = (const float*)d_in[4];
  const float* bias_tab= (const float*)d_in[5];
  const float* ln1_g   = (const float*)d_in[6];
  const float* ln1_b   = (const float*)d_in[7];
  const float* ln2_g   = (const float*)d_in[8];
  const float* ln2_b   = (const float*)d_in[9];
  const float* mlp_w1  = (const float*)d_in[10];
  const float* mlp_b1  = (const float*)d_in[11];
  const float* mlp_w2  = (const float*)d_in[12];
  const float* mlp_b2  = (const float*)d_in[13];

  const int nElem = L_TOK * 192;
  float* xf = (float*)d_out;

  const size_t sz_R0 = 159252480;  // bf16 qkv L*576 (Q-slice becomes attn out)
  const size_t sz_xb = 53084160;   // bf16 residual stream
  const size_t sz_wT = 1769472;
  const size_t sz_bb = 2488320;
  const size_t sz_qb = 4608;
  const size_t need  = sz_R0 + sz_xb + sz_wT + sz_bb + sz_qb;   // ~216.6 MB

  if (ws_size < need) {
    copy_diag<<<dim3((nElem+255)/256), 256, 0, stream>>>(x_in, xf, nElem);
    return;
  }

  char* ws = (char*)d_ws;
  unsigned short* R0    = (unsigned short*)(ws);
  unsigned short* xb    = (unsigned short*)(ws + sz_R0);
  unsigned short* wT    = (unsigned short*)(ws + sz_R0 + sz_xb);
  unsigned short* biasb = (unsigned short*)(ws + sz_R0 + sz_xb + sz_wT);
  float*          qb2   = (float*)(ws + sz_R0 + sz_xb + sz_wT + sz_bb);

  unsigned short* wT_qkv  = wT;
  unsigned short* wT_proj = wT + 221184;
  unsigned short* wT_m1   = wT + 294912;
  unsigned short* wT_m2   = wT + 589824;

  transpose_w<<<dim3((2*192*576+255)/256), 256, 0, stream>>>(qkv_w,  wT_qkv, 192, 576, 192, 0.17677669529663687f);
  transpose_w<<<dim3((2*192*192+255)/256), 256, 0, stream>>>(proj_w, wT_proj,192, 192, 0, 1.0f);
  transpose_w<<<dim3((2*192*768+255)/256), 256, 0, stream>>>(mlp_w1, wT_m1,  192, 768, 0, 1.0f);
  transpose_w<<<dim3((2*768*192+255)/256), 256, 0, stream>>>(mlp_w2, wT_m2,  768, 192, 0, 1.0f);
  build_biasb6<<<dim3((5*6*144*144+255)/256), 256, 0, stream>>>(bias_tab, biasb);
  scale_qb<<<dim3(5), 256, 0, stream>>>(qkv_b, qb2);

  init_xb<<<dim3((nElem+255)/256), 256, 0, stream>>>(x_in, xb, nElem);

  for (int i = 0; i < 2; i++) {
    gemm_qkv<9><<<dim3(2160), 256, 0, stream>>>(
        xb, wT_qkv + (size_t)i*110592, qb2 + i*576, R0);
    attn_win7<<<dim3(NW), 384, 0, stream>>>(
        R0, biasb + (i ? 124416 : 0), i & 1);
    gemm_ln<<<dim3(1080), 256, 0, stream>>>(
        R0, wT_proj + (size_t)i*36864, proj_b + i*192,
        ln1_g + i*192, ln1_b + i*192, xb, 576);
    if (i == 0)
      fused_mlp<0><<<dim3(4320), 256, 0, stream>>>(
          xb, wT_m1, wT_m2, mlp_b1, mlp_b2,
          ln2_g, ln2_b, xb, nullptr);
    else
      fused_mlp<1><<<dim3(4320), 256, 0, stream>>>(
          xb, wT_m1 + (size_t)147456, wT_m2 + (size_t)147456,
          mlp_b1 + 768, mlp_b2 + 192,
          ln2_g + 192, ln2_b + 192, xb, xf);
  }
}

// Round 15
// 880.250 us; speedup vs baseline: 1.2448x; 1.2448x over previous
//
#include <hip/hip_runtime.h>
#include <hip/hip_bf16.h>
#include <math.h>

#define L_TOK 138240
#define NW 960

typedef __attribute__((ext_vector_type(8))) short s16x8;
typedef __attribute__((ext_vector_type(8))) unsigned short u16x8;
typedef __attribute__((ext_vector_type(4))) unsigned short u16x4;
typedef __attribute__((ext_vector_type(4))) float f32x4;

__device__ __forceinline__ float bf2f(unsigned short u){
  union{unsigned int u;float f;} v; v.u=((unsigned int)u)<<16; return v.f;
}
__device__ __forceinline__ unsigned short f2bf(float f){
  __hip_bfloat16 b = __float2bfloat16(f);
  union { __hip_bfloat16 b; unsigned short u; } v; v.b = b; return v.u;
}
__device__ __forceinline__ void gll16(const void* g, void* l) {
  __builtin_amdgcn_global_load_lds((const __attribute__((address_space(1))) void*)g,
                                   (__attribute__((address_space(3))) void*)l, 16, 0, 0);
}
// exact-gelu via A&S 7.1.26 erf (max abs err 1.5e-7 << bf16 ulp)
__device__ __forceinline__ float gelu_f(float v){
  const float s = v * 0.70710678118654752f;
  const float a = fabsf(s);
  const float t = 1.0f / (1.0f + 0.3275911f * a);
  float p = 1.061405429f;
  p = p*t - 1.453152027f;
  p = p*t + 1.421413741f;
  p = p*t - 0.284496736f;
  p = p*t + 0.254829592f;
  p = p*t;
  float y = 1.0f - p * __expf(-a*a);
  y = copysignf(y, s);
  return 0.5f * v * (1.0f + y);
}

// ============ QKV GEMM: A = xb bf16 (gll16, swizzled), 64-row stripes ============
template<int NTILES>
__global__ __launch_bounds__(256) void gemm_qkv(
    const unsigned short* __restrict__ xb,   // L x 192 bf16
    const unsigned short* __restrict__ Bt,   // N x 192 bf16
    const float* __restrict__ bias,
    unsigned short* __restrict__ out)        // L x N
{
  __shared__ unsigned short As[64*192];      // linear, swizzled via global src
  const int tid = threadIdx.x;
  const int wid = tid >> 6, lane = tid & 63;
  const int lr = lane & 15, kg = lane >> 4;
  const int bm = blockIdx.x;
  const int wn = wid * 16;
  const int N = NTILES * 64;

  #pragma unroll
  for (int i = 0; i < 6; i++) {
    const int c = tid + i*256;
    const int r = c / 24, s = c % 24;
    const int sg = (s & 24) | ((s ^ r) & 7);   // pre-swizzled source slot
    gll16(&xb[(size_t)(bm*64 + r)*192 + sg*8], &As[c*8]);
  }
  __syncthreads();

  s16x8 a[4][6];
  #pragma unroll
  for (int mi = 0; mi < 4; mi++)
    #pragma unroll
    for (int ks = 0; ks < 6; ks++) {
      const int m = mi*16 + lr, g = ks*4 + kg;
      const int sg = (g & 24) | ((g ^ m) & 7);
      a[mi][ks] = *(const s16x8*)&As[m*192 + sg*8];
    }

  for (int bn = 0; bn < NTILES; bn++) {
    s16x8 b[6];
    #pragma unroll
    for (int ks = 0; ks < 6; ks++)
      b[ks] = *(const s16x8*)&Bt[(size_t)(bn*64 + wn + lr)*192 + ks*32 + kg*8];
    f32x4 acc[4] = {};
    #pragma unroll
    for (int ks = 0; ks < 6; ks++)
      #pragma unroll
      for (int mi = 0; mi < 4; mi++)
        acc[mi] = __builtin_amdgcn_mfma_f32_16x16x32_bf16(a[mi][ks], b[ks], acc[mi], 0, 0, 0);
    const int col = bn*64 + wn + lr;
    const float bv = bias[col];
    #pragma unroll
    for (int mi = 0; mi < 4; mi++)
      #pragma unroll
      for (int q = 0; q < 4; q++) {
        const int row = bm*64 + mi*16 + kg*4 + q;
        out[(size_t)row*N + col] = f2bf(acc[mi][q] + bv);
      }
  }
}

// ============ proj GEMM + LN residual: xb += LN(A @ Bt^T + bias) (bf16 RMW) ============
__global__ __launch_bounds__(256) void gemm_ln(
    const unsigned short* __restrict__ A,    // rows at stride lda (AO in R0)
    const unsigned short* __restrict__ Bt,   // 192 x 192 bf16
    const float* __restrict__ bias, const float* __restrict__ g,
    const float* __restrict__ bta,
    unsigned short* __restrict__ xbo,
    int lda)
{
  __shared__ unsigned short As[2][128*32];
  __shared__ unsigned short Bs[2][192*32];
  __shared__ float rowstat[128][2][2];
  const int tid = threadIdx.x;
  const int wid = tid >> 6, lane = tid & 63;
  const int lr = lane & 15, kg = lane >> 4;
  const int bm = blockIdx.x;
  const int wm = (wid >> 1) * 64, wn = (wid & 1) * 96;
  const int rsub = lane >> 2, kc = lane & 3;
  const int K = 192;

  f32x4 acc[4][6] = {};
  const int nst = K / 32;

  #pragma unroll
  for (int i = 0; i < 2; i++)
    gll16(&A[(size_t)(bm*128 + wid*32 + i*16 + rsub)*lda + kc*8], &As[0][(wid*32 + i*16)*32]);
  #pragma unroll
  for (int j = 0; j < 3; j++)
    gll16(&Bt[(size_t)(wid*48 + j*16 + rsub)*K + kc*8], &Bs[0][(wid*48 + j*16)*32]);
  __syncthreads();

  for (int t = 0; t < nst; t++) {
    const int cur = t & 1, nxt = cur ^ 1;
    if (t + 1 < nst) {
      const int k1 = (t+1)*32;
      #pragma unroll
      for (int i = 0; i < 2; i++)
        gll16(&A[(size_t)(bm*128 + wid*32 + i*16 + rsub)*lda + k1 + kc*8], &As[nxt][(wid*32 + i*16)*32]);
      #pragma unroll
      for (int j = 0; j < 3; j++)
        gll16(&Bt[(size_t)(wid*48 + j*16 + rsub)*K + k1 + kc*8], &Bs[nxt][(wid*48 + j*16)*32]);
    }
    s16x8 a[4], b[6];
    #pragma unroll
    for (int mi = 0; mi < 4; mi++) a[mi] = *(const s16x8*)&As[cur][(wm + mi*16 + lr)*32 + kg*8];
    #pragma unroll
    for (int ni = 0; ni < 6; ni++) b[ni] = *(const s16x8*)&Bs[cur][(wn + ni*16 + lr)*32 + kg*8];
    #pragma unroll
    for (int mi = 0; mi < 4; mi++)
      #pragma unroll
      for (int ni = 0; ni < 6; ni++)
        acc[mi][ni] = __builtin_amdgcn_mfma_f32_16x16x32_bf16(a[mi], b[ni], acc[mi][ni], 0, 0, 0);
    __syncthreads();
  }

  float bv[6], gv[6], btv[6];
  #pragma unroll
  for (int ni = 0; ni < 6; ni++) {
    const int col = wn + ni*16 + lr;
    bv[ni] = bias[col]; gv[ni] = g[col]; btv[ni] = bta[col];
  }
  #pragma unroll
  for (int mi = 0; mi < 4; mi++) {
    float s[4] = {0,0,0,0}, ss[4] = {0,0,0,0};
    #pragma unroll
    for (int ni = 0; ni < 6; ni++)
      #pragma unroll
      for (int q = 0; q < 4; q++) {
        const float v = acc[mi][ni][q] + bv[ni];
        s[q] += v; ss[q] += v*v;
      }
    #pragma unroll
    for (int q = 0; q < 4; q++) {
      #pragma unroll
      for (int m = 1; m < 16; m <<= 1) {
        s[q]  += __shfl_xor(s[q],  m, 64);
        ss[q] += __shfl_xor(ss[q], m, 64);
      }
    }
    if (lr == 0) {
      #pragma unroll
      for (int q = 0; q < 4; q++) {
        const int r = wm + mi*16 + kg*4 + q;
        rowstat[r][wid & 1][0] = s[q];
        rowstat[r][wid & 1][1] = ss[q];
      }
    }
  }
  __syncthreads();
  #pragma unroll
  for (int mi = 0; mi < 4; mi++) {
    #pragma unroll
    for (int q = 0; q < 4; q++) {
      const int rl = wm + mi*16 + kg*4 + q;
      const float s  = rowstat[rl][0][0] + rowstat[rl][1][0];
      const float ss = rowstat[rl][0][1] + rowstat[rl][1][1];
      const float mu = s * (1.0f/192.0f);
      const float rs = rsqrtf(ss * (1.0f/192.0f) - mu*mu + 1e-5f);
      const size_t grow = (size_t)(bm*128 + rl) * 192;
      #pragma unroll
      for (int ni = 0; ni < 6; ni++) {
        const float v = acc[mi][ni][q] + bv[ni];
        const float o = (v - mu) * rs * gv[ni] + btv[ni];
        const size_t idx = grow + wn + ni*16 + lr;
        xbo[idx] = f2bf(bf2f(xbo[idx]) + o);
      }
    }
  }
}

// ============ Fused MLP (BM=64, dbuf Hs, 1 barrier/t): xb += LN(gelu(xb@W1+b1)@W2+b2) ============
template<int WF32>
__global__ __launch_bounds__(256) void fused_mlp(
    const unsigned short* __restrict__ xb,   // L x 192 bf16 (also RMW target)
    const unsigned short* __restrict__ W1t,  // 768 x 192 bf16
    const unsigned short* __restrict__ W2t,  // 192 x 768 bf16
    const float* __restrict__ b1, const float* __restrict__ b2,
    const float* __restrict__ g, const float* __restrict__ bt,
    unsigned short* __restrict__ xbo, float* __restrict__ xf)
{
  __shared__ unsigned short As[64*192];      // swizzled (via global src), 24 KB
  __shared__ unsigned short Hs[2][64*64];    // double buffer, 128B rows, XOR-swizzled, 16 KB
  __shared__ float rowstat[64][4][2];
  const int tid = threadIdx.x, wid = tid >> 6, lane = tid & 63;
  const int lr = lane & 15, kg = lane >> 4;
  const int row0 = blockIdx.x * 64;

  #pragma unroll
  for (int i = 0; i < 6; i++) {
    const int c = tid + i*256;
    const int r = c / 24, s = c % 24;
    const int sg = (s & 24) | ((s ^ r) & 7);
    gll16(&xb[(size_t)(row0 + r)*192 + sg*8], &As[c*8]);
  }
  __syncthreads();

  char* const hs0 = (char*)&Hs[0][0];
  char* const hs1 = (char*)&Hs[1][0];

  f32x4 yacc[4][3] = {};
  // prefetch W1 fragments for t=0
  s16x8 w1f[6];
  #pragma unroll
  for (int ks = 0; ks < 6; ks++)
    w1f[ks] = *(const s16x8*)&W1t[(size_t)(wid*16 + lr)*192 + ks*32 + kg*8];

  for (int t = 0; t < 12; t++) {
    char* const hb = (t & 1) ? hs1 : hs0;
    // GEMM1 (swapped): h^T = mfma(W1 rows=h-cols, x rows=m)
    f32x4 hacc[4];
    #pragma unroll
    for (int mb = 0; mb < 4; mb++) {
      const int m = mb*16 + lr;
      hacc[mb] = f32x4{0.f, 0.f, 0.f, 0.f};
      #pragma unroll
      for (int ks = 0; ks < 6; ks++) {
        const int gsl = ks*4 + kg;
        const int sg = (gsl & 24) | ((gsl ^ m) & 7);
        const s16x8 xf8 = *(const s16x8*)&As[m*192 + sg*8];
        hacc[mb] = __builtin_amdgcn_mfma_f32_16x16x32_bf16(w1f[ks], xf8, hacc[mb], 0, 0, 0);
      }
    }
    // prefetch GEMM2 weight fragments for this t (off the barrier path)
    s16x8 b2f[6];
    #pragma unroll
    for (int kk = 0; kk < 2; kk++)
      #pragma unroll
      for (int nj = 0; nj < 3; nj++)
        b2f[kk*3 + nj] = *(const s16x8*)&W2t[(size_t)(wid*48 + nj*16 + lr)*768 + t*64 + kk*32 + kg*8];

    const float4 b1q = *(const float4*)&b1[t*64 + wid*16 + kg*4];
    {
      const int cb = wid*32 + kg*8;
      #pragma unroll
      for (int mb = 0; mb < 4; mb++) {
        const int m = mb*16 + lr;
        u16x4 hv;
        hv[0] = f2bf(gelu_f(hacc[mb][0] + b1q.x));
        hv[1] = f2bf(gelu_f(hacc[mb][1] + b1q.y));
        hv[2] = f2bf(gelu_f(hacc[mb][2] + b1q.z));
        hv[3] = f2bf(gelu_f(hacc[mb][3] + b1q.w));
        *(u16x4*)(hb + m*128 + (cb ^ ((m & 7) << 4))) = hv;
      }
    }
    __syncthreads();                       // Hs[t&1] ready; also fences buf reuse (see dbuf arg)
    // prefetch next-t W1 fragments (off the GEMM2 path)
    if (t < 11) {
      #pragma unroll
      for (int ks = 0; ks < 6; ks++)
        w1f[ks] = *(const s16x8*)&W1t[(size_t)((t+1)*64 + wid*16 + lr)*192 + ks*32 + kg*8];
    }
    // GEMM2: y += h_tile @ W2[:, t*64..]
    #pragma unroll
    for (int kk = 0; kk < 2; kk++) {
      #pragma unroll
      for (int mi = 0; mi < 4; mi++) {
        const int m = mi*16 + lr;
        const int cb2 = kk*64 + kg*16;
        const s16x8 a2 = *(const s16x8*)(hb + m*128 + (cb2 ^ ((m & 7) << 4)));
        #pragma unroll
        for (int nj = 0; nj < 3; nj++)
          yacc[mi][nj] = __builtin_amdgcn_mfma_f32_16x16x32_bf16(a2, b2f[kk*3 + nj], yacc[mi][nj], 0, 0, 0);
      }
    }
  }

  float bv[3], gv[3], btv[3];
  #pragma unroll
  for (int nj = 0; nj < 3; nj++) {
    const int col = wid*48 + nj*16 + lr;
    bv[nj] = b2[col]; gv[nj] = g[col]; btv[nj] = bt[col];
  }
  #pragma unroll
  for (int mi = 0; mi < 4; mi++) {
    float s[4] = {0,0,0,0}, ss[4] = {0,0,0,0};
    #pragma unroll
    for (int nj = 0; nj < 3; nj++)
      #pragma unroll
      for (int q = 0; q < 4; q++) {
        const float v = yacc[mi][nj][q] + bv[nj];
        s[q] += v; ss[q] += v*v;
      }
    #pragma unroll
    for (int q = 0; q < 4; q++) {
      #pragma unroll
      for (int m = 1; m < 16; m <<= 1) {
        s[q]  += __shfl_xor(s[q],  m, 64);
        ss[q] += __shfl_xor(ss[q], m, 64);
      }
    }
    if (lr == 0) {
      #pragma unroll
      for (int q = 0; q < 4; q++) {
        rowstat[mi*16 + kg*4 + q][wid][0] = s[q];
        rowstat[mi*16 + kg*4 + q][wid][1] = ss[q];
      }
    }
  }
  __syncthreads();
  #pragma unroll
  for (int mi = 0; mi < 4; mi++) {
    #pragma unroll
    for (int q = 0; q < 4; q++) {
      const int rl = mi*16 + kg*4 + q;
      const float s  = rowstat[rl][0][0] + rowstat[rl][1][0] + rowstat[rl][2][0] + rowstat[rl][3][0];
      const float ss = rowstat[rl][0][1] + rowstat[rl][1][1] + rowstat[rl][2][1] + rowstat[rl][3][1];
      const float mu = s * (1.0f/192.0f);
      const float rs = rsqrtf(ss * (1.0f/192.0f) - mu*mu + 1e-5f);
      const size_t grow = (size_t)(row0 + rl) * 192;
      #pragma unroll
      for (int nj = 0; nj < 3; nj++) {
        const float v = yacc[mi][nj][q] + bv[nj];
        const float o = (v - mu) * rs * gv[nj] + btv[nj];
        const size_t idx = grow + wid*48 + nj*16 + lr;
        const float xn = bf2f(xbo[idx]) + o;
        xbo[idx] = f2bf(xn);
        if (WF32) xf[idx] = xn;
      }
    }
  }
}

// ============ Window attention v7: in-place output over Q-slice of qkv ============
__global__ __launch_bounds__(384) void attn_win7(
    unsigned short* qkv,                       // L x 576 bf16 (Q pre-scaled; Q-slice overwritten)
    const unsigned short* __restrict__ biasbt, // [class][head][s][ti][lr][c4] bf16
    int roll)
{
  __shared__ unsigned short Pw[6][16][168];
  __shared__ int lmap[144];

  const int w = blockIdx.x;
  const int tid = threadIdx.x, wid = tid / 64, lane = tid & 63;
  const int lr = lane & 15, kg = lane >> 4;
  const int ww = w % 15, hw = (w / 15) % 16, zw = w / 240;

  if (tid < 144) {
    const int z1 = tid / 72, h1 = (tid % 72) / 12, w1 = tid % 12;
    int z = zw*2 + z1, h = hw*6 + h1, xx = ww*12 + w1;
    if (roll) { z = (z + 1) & 7; h = (h + 3) % 96; xx = (xx + 6) % 180; }
    lmap[tid] = (z*96 + h)*180 + xx;
  }
  __syncthreads();

  const unsigned short* bb;
  if (roll) {
    const int c = ((zw == 3) ? 2 : 0) | ((hw == 15) ? 1 : 0);
    bb = biasbt + (size_t)c*124416 + (size_t)wid*20736;
  } else {
    bb = biasbt + (size_t)wid*20736;
  }

  s16x8 kfr[9];
  #pragma unroll
  for (int ti = 0; ti < 9; ti++)
    kfr[ti] = *(const s16x8*)&qkv[(size_t)lmap[ti*16 + lr]*576 + 192 + wid*32 + kg*8];

  s16x8 vbr[2][5];
  #pragma unroll
  for (int ci = 0; ci < 2; ci++)
    #pragma unroll
    for (int ks = 0; ks < 5; ks++) {
      u16x8 t;
      #pragma unroll
      for (int j = 0; j < 8; j++) {
        const int tok = ks*32 + kg*8 + j;
        t[j] = (tok < 144) ? qkv[(size_t)lmap[tok]*576 + 384 + wid*32 + ci*16 + lr] : (unsigned short)0;
      }
      vbr[ci][ks] = (s16x8)t;
    }

  #pragma unroll
  for (int j = 0; j < 4; j++) Pw[wid][lr][144 + kg*4 + j] = 0;

  for (int s = 0; s < 9; s++) {
    const s16x8 bq = *(const s16x8*)&qkv[(size_t)lmap[s*16 + lr]*576 + wid*32 + kg*8];

    float pb[9][4];
    float mx = -3.0e38f;
    #pragma unroll
    for (int ti = 0; ti < 9; ti++) {
      f32x4 acc = {0.f, 0.f, 0.f, 0.f};
      acc = __builtin_amdgcn_mfma_f32_16x16x32_bf16(kfr[ti], bq, acc, 0, 0, 0);
      const u16x4 b4 = *(const u16x4*)&bb[(size_t)(s*9 + ti)*256 + lr*16 + kg*4];
      #pragma unroll
      for (int q = 0; q < 4; q++) {
        const float sv = acc[q] + bf2f(b4[q]);
        pb[ti][q] = sv;
        mx = fmaxf(mx, sv);
      }
    }
    mx = fmaxf(mx, __shfl_xor(mx, 16, 64));
    mx = fmaxf(mx, __shfl_xor(mx, 32, 64));

    float sum = 0.f;
    #pragma unroll
    for (int ti = 0; ti < 9; ti++)
      #pragma unroll
      for (int q = 0; q < 4; q++) {
        const float p = __expf(pb[ti][q] - mx);
        pb[ti][q] = p;
        sum += p;
      }
    sum += __shfl_xor(sum, 16, 64);
    sum += __shfl_xor(sum, 32, 64);
    const float inv = 1.0f / sum;

    #pragma unroll
    for (int ti = 0; ti < 9; ti++)
      #pragma unroll
      for (int q = 0; q < 4; q++)
        Pw[wid][lr][ti*16 + kg*4 + q] = f2bf(pb[ti][q] * inv);

    #pragma unroll
    for (int ci = 0; ci < 2; ci++) {
      f32x4 accO = {0.f, 0.f, 0.f, 0.f};
      #pragma unroll
      for (int ks = 0; ks < 5; ks++) {
        const s16x8 pa = *(const s16x8*)&Pw[wid][lr][ks*32 + kg*8];
        accO = __builtin_amdgcn_mfma_f32_16x16x32_bf16(pa, vbr[ci][ks], accO, 0, 0, 0);
      }
      #pragma unroll
      for (int q = 0; q < 4; q++) {
        const int row = s*16 + kg*4 + q;
        qkv[(size_t)lmap[row]*576 + wid*32 + ci*16 + lr] = f2bf(accO[q]);
      }
    }
  }
}

// ============ helpers ============
__global__ void init_xb(const float* __restrict__ xin, unsigned short* __restrict__ xb, int n) {
  const int i = blockIdx.x*256 + threadIdx.x;
  if (i < n) xb[i] = f2bf(xin[i]);
}
__global__ void copy_diag(const float* __restrict__ a, float* __restrict__ o, int n) {
  const int i = blockIdx.x*256 + threadIdx.x;
  if (i < n) o[i] = a[i] + 50.0f;
}
__global__ void transpose_w(const float* __restrict__ src, unsigned short* __restrict__ dst,
                            int K, int N, int nscale, float factor) {
  const int i = blockIdx.x*256 + threadIdx.x;
  const int tot = K*N;
  if (i >= 2*tot) return;
  const int l = i / tot, e = i % tot;
  const int k = e / N, n = e % N;
  float v = src[i];
  if (n < nscale) v *= factor;
  dst[(size_t)l*tot + (size_t)n*K + k] = f2bf(v);
}
__global__ void scale_qb(const float* __restrict__ src, float* __restrict__ dst) {
  const int i = blockIdx.x*256 + threadIdx.x;
  if (i >= 2*576) return;
  const float f = (i % 576) < 192 ? 0.17677669529663687f : 1.0f;
  dst[i] = src[i] * f;
}
// 5 tables lane-coalesced: [tau][head][s(9)][ti(9)][lr(16)][c4(16)]
__global__ void build_biasb6(const float* __restrict__ tab, unsigned short* __restrict__ bm) {
  const int i = blockIdx.x*256 + threadIdx.x;
  const int TAB = 6*144*144;
  if (i >= 5*TAB) return;
  const int tau = i / TAB, r = i % TAB;
  const int hd = r / 20736, rr = r % 20736;
  const int s = rr / 2304, rrr = rr % 2304;
  const int ti = rrr / 256, e = rrr % 256;
  const int lr_ = e / 16, c4 = e % 16;
  const int q = s*16 + lr_, tok = ti*16 + c4;
  const int z1 = q/72,  h1 = (q%72)/12,  w1 = q%12;
  const int z2 = tok/72, h2 = (tok%72)/12, w2 = tok%12;
  const int idx = (z1 + 2*z2)*828 + (h1 + 6*h2)*23 + (w1 - w2 + 11);
  const int l = (tau == 0) ? 0 : 1;
  float v = tab[(size_t)l*3312*6 + (size_t)idx*6 + hd];
  if (tau >= 1) {
    const int c = tau - 1, zs = c >> 1, hs = c & 1;
    const int rq = (zs ? (1 + z1) : 0)*3 + (hs ? (1 + (h1 >= 3)) : 0);
    const int rt = (zs ? (1 + z2) : 0)*3 + (hs ? (1 + (h2 >= 3)) : 0);
    if (rq != rt) v -= 1.0e9f;
  }
  bm[i] = f2bf(v);
}

extern "C" void kernel_launch(void* const* d_in, const int* in_sizes, int n_in,
                              void* d_out, int out_size, void* d_ws, size_t ws_size,
                              hipStream_t stream) {
  const float* x_in    = (const float*)d_in[0];
  const float* qkv_w   = (const float*)d_in[1];
  const float* qkv_b   = (const float*)d_in[2];
  const float* proj_w  = (const float*)d_in[3];
  const float* proj_b  = (const float*)d_in[4];
  const float* bias_tab= (const float*)d_in[5];
  const float* ln1_g   = (const float*)d_in[6];
  const float* ln1_b   = (const float*)d_in[7];
  const float* ln2_g   = (const float*)d_in[8];
  const float* ln2_b   = (const float*)d_in[9];
  const float* mlp_w1  = (const float*)d_in[10];
  const float* mlp_b1  = (const float*)d_in[11];
  const float* mlp_w2  = (const float*)d_in[12];
  const float* mlp_b2  = (const float*)d_in[13];

  const int nElem = L_TOK * 192;
  float* xf = (float*)d_out;

  const size_t sz_R0 = 159252480;  // bf16 qkv L*576 (Q-slice becomes attn out)
  const size_t sz_xb = 53084160;   // bf16 residual stream
  const size_t sz_wT = 1769472;
  const size_t sz_bb = 2488320;
  const size_t sz_qb = 4608;
  const size_t need  = sz_R0 + sz_xb + sz_wT + sz_bb + sz_qb;   // ~216.6 MB

  if (ws_size < need) {
    copy_diag<<<dim3((nElem+255)/256), 256, 0, stream>>>(x_in, xf, nElem);
    return;
  }

  char* ws = (char*)d_ws;
  unsigned short* R0    = (unsigned short*)(ws);
  unsigned short* xb    = (unsigned short*)(ws + sz_R0);
  unsigned short* wT    = (unsigned short*)(ws + sz_R0 + sz_xb);
  unsigned short* biasb = (unsigned short*)(ws + sz_R0 + sz_xb + sz_wT);
  float*          qb2   = (float*)(ws + sz_R0 + sz_xb + sz_wT + sz_bb);

  unsigned short* wT_qkv  = wT;
  unsigned short* wT_proj = wT + 221184;
  unsigned short* wT_m1   = wT + 294912;
  unsigned short* wT_m2   = wT + 589824;

  transpose_w<<<dim3((2*192*576+255)/256), 256, 0, stream>>>(qkv_w,  wT_qkv, 192, 576, 192, 0.17677669529663687f);
  transpose_w<<<dim3((2*192*192+255)/256), 256, 0, stream>>>(proj_w, wT_proj,192, 192, 0, 1.0f);
  transpose_w<<<dim3((2*192*768+255)/256), 256, 0, stream>>>(mlp_w1, wT_m1,  192, 768, 0, 1.0f);
  transpose_w<<<dim3((2*768*192+255)/256), 256, 0, stream>>>(mlp_w2, wT_m2,  768, 192, 0, 1.0f);
  build_biasb6<<<dim3((5*6*144*144+255)/256), 256, 0, stream>>>(bias_tab, biasb);
  scale_qb<<<dim3(5), 256, 0, stream>>>(qkv_b, qb2);

  init_xb<<<dim3((nElem+255)/256), 256, 0, stream>>>(x_in, xb, nElem);

  for (int i = 0; i < 2; i++) {
    gemm_qkv<9><<<dim3(2160), 256, 0, stream>>>(
        xb, wT_qkv + (size_t)i*110592, qb2 + i*576, R0);
    attn_win7<<<dim3(NW), 384, 0, stream>>>(
        R0, biasb + (i ? 124416 : 0), i & 1);
    gemm_ln<<<dim3(1080), 256, 0, stream>>>(
        R0, wT_proj + (size_t)i*36864, proj_b + i*192,
        ln1_g + i*192, ln1_b + i*192, xb, 576);
    if (i == 0)
      fused_mlp<0><<<dim3(2160), 256, 0, stream>>>(
          xb, wT_m1, wT_m2, mlp_b1, mlp_b2,
          ln2_g, ln2_b, xb, nullptr);
    else
      fused_mlp<1><<<dim3(2160), 256, 0, stream>>>(
          xb, wT_m1 + (size_t)147456, wT_m2 + (size_t)147456,
          mlp_b1 + 768, mlp_b2 + 192,
          ln2_g + 192, ln2_b + 192, xb, xf);
  }
}